// Round 2
// baseline (578.006 us; speedup 1.0000x reference)
//
#include <hip/hip_runtime.h>
#include <hip/hip_bf16.h>

typedef __bf16 bf16x8 __attribute__((ext_vector_type(8)));
typedef float f32x4 __attribute__((ext_vector_type(4)));
typedef unsigned short u16x8 __attribute__((ext_vector_type(8)));

static __device__ __forceinline__ unsigned short f2bf(float f){
  unsigned int u = __float_as_uint(f);
  u += 0x7fffu + ((u >> 16) & 1u);   // round-to-nearest-even
  return (unsigned short)(u >> 16);
}

static __device__ __forceinline__ u16x8 cvt8(const float4& a, const float4& b){
  u16x8 r;
  r[0]=f2bf(a.x); r[1]=f2bf(a.y); r[2]=f2bf(a.z); r[3]=f2bf(a.w);
  r[4]=f2bf(b.x); r[5]=f2bf(b.y); r[6]=f2bf(b.z); r[7]=f2bf(b.w);
  return r;
}

// raw staged data for 16 elems (one thread's half-row slice)
template<typename T> struct Stg;
template<> struct Stg<unsigned short> { u16x8 v[2]; };
template<> struct Stg<float>          { float4 v[4]; };

template<typename T>
static __device__ __forceinline__ void stg_load(Stg<T>& s, const T* __restrict__ p,
                                                bool rok, int c0, int kend){
  // 16 elems at columns c0..c0+15, zero-guarded per 8 (K, kchunk are mult of 8)
  if constexpr (sizeof(T)==2){
    s.v[0] = (rok && c0     < kend) ? *(const u16x8*)(p)   : (u16x8)0;
    s.v[1] = (rok && c0 + 8 < kend) ? *(const u16x8*)(p+8) : (u16x8)0;
  } else {
    const bool o0 = rok && c0 < kend, o1 = rok && (c0+8) < kend;
    const float4* q = (const float4*)p;
    const float4 z4 = {0.f,0.f,0.f,0.f};
    s.v[0] = o0 ? q[0] : z4;  s.v[1] = o0 ? q[1] : z4;
    s.v[2] = o1 ? q[2] : z4;  s.v[3] = o1 ? q[3] : z4;
  }
}

template<typename T>
static __device__ __forceinline__ void stg_write(unsigned short* d, const Stg<T>& s){
  if constexpr (sizeof(T)==2){
    *(u16x8*)(d)   = s.v[0];
    *(u16x8*)(d+8) = s.v[1];
  } else {
    *(u16x8*)(d)   = cvt8(s.v[0], s.v[1]);
    *(u16x8*)(d+8) = cvt8(s.v[2], s.v[3]);
  }
}

// C[m,n] = epi( sum_k A[m,k]*B[n,k] )  — A:[M][K], B:[N][K] row-major (both ld=K)
// EPI 0: Cf = acc + bias(optional)   EPI 1: atomicAdd(Cf, acc)   EPI 2: Cbf = bf16(tanh(acc+bias))
// Double-buffered LDS, register prefetch issued 2 K-steps ahead (latency hiding).
template<typename TA, typename TB, int EPI>
__global__ __launch_bounds__(256) void gemm_bt(
    const TA* __restrict__ A, const TB* __restrict__ B,
    const float* __restrict__ bias,
    float* __restrict__ Cf, unsigned short* __restrict__ Cbf,
    int M, int N, int K, int kchunk)
{
  constexpr int BM = 128, BN = 128, BK = 32, SA = 40; // SA: padded LDS row stride
  __shared__ unsigned short lds[2 * (BM + BN) * SA];  // 40 KB

  const int tid  = threadIdx.x;
  const int bm0  = blockIdx.y * BM, bn0 = blockIdx.x * BN;
  const int k0   = blockIdx.z * kchunk;
  const int kend = min(K, k0 + kchunk);
  const int lane = tid & 63, wave = tid >> 6;
  const int wm = (wave >> 1) * 64, wn = (wave & 1) * 64; // 2x2 waves, 64x64 each
  const int fr = lane & 15, fq = lane >> 4;
  const int srow = tid >> 1, shalf = tid & 1;            // staging: 2 thr/row, 16 elems each

  const int  nk   = (kend - k0 + BK - 1) / BK;
  const bool arok = (bm0 + srow) < M;
  const bool brok = (bn0 + srow) < N;
  const TA* Abase = A + (size_t)(bm0 + srow) * K + shalf * 16;
  const TB* Bbase = B + (size_t)(bn0 + srow) * K + shalf * 16;

  Stg<TA> sa; Stg<TB> sb;
  auto issue = [&](int kidx){
    const int c0 = k0 + kidx * BK + shalf * 16;
    stg_load(sa, Abase + k0 + kidx * BK, arok, c0, kend);
    stg_load(sb, Bbase + k0 + kidx * BK, brok, c0, kend);
  };

  unsigned short* cur = lds;
  unsigned short* nxt = lds + (BM + BN) * SA;

  issue(0);
  stg_write(cur + srow * SA + shalf * 16, sa);
  stg_write(cur + BM * SA + srow * SA + shalf * 16, sb);
  if (nk > 1) issue(1);

  f32x4 acc[4][4] = {};

  for (int k = 0; k < nk; k++) {
    __syncthreads();                       // lds[cur] fully written, prev reads drained
    u16x8 af[4], bg[4];
    #pragma unroll
    for (int i = 0; i < 4; i++) af[i] = *(const u16x8*)&cur[(wm + i*16 + fr)*SA + fq*8];
    #pragma unroll
    for (int j = 0; j < 4; j++) bg[j] = *(const u16x8*)&cur[BM*SA + (wn + j*16 + fr)*SA + fq*8];
    if (k + 1 < nk) {                      // write next buffer (waits vmcnt of load k+1)
      stg_write(nxt + srow * SA + shalf * 16, sa);
      stg_write(nxt + BM * SA + srow * SA + shalf * 16, sb);
      if (k + 2 < nk) issue(k + 2);        // in flight across next full iteration
    }
    #pragma unroll
    for (int i = 0; i < 4; i++)
      #pragma unroll
      for (int j = 0; j < 4; j++)
        acc[i][j] = __builtin_amdgcn_mfma_f32_16x16x32_bf16(
            __builtin_bit_cast(bf16x8, af[i]),
            __builtin_bit_cast(bf16x8, bg[j]),
            acc[i][j], 0, 0, 0);
    unsigned short* t = cur; cur = nxt; nxt = t;
  }

  #pragma unroll
  for (int i = 0; i < 4; i++)
    #pragma unroll
    for (int j = 0; j < 4; j++)
      #pragma unroll
      for (int r = 0; r < 4; r++) {
        int row = bm0 + wm + i*16 + fq*4 + r;
        int col = bn0 + wn + j*16 + fr;
        if (row < M && col < N) {
          float v = acc[i][j][r];
          if constexpr (EPI == 0) {
            Cf[(size_t)row * N + col] = v + (bias ? bias[col] : 0.0f);
          } else if constexpr (EPI == 1) {
            atomicAdd(&Cf[(size_t)row * N + col], v);
          } else {
            Cbf[(size_t)row * N + col] = f2bf(tanhf(v + bias[col]));
          }
        }
      }
}

// per-row: y = bf16(x*dm); ninv = 1/max(||x||,1e-12)
__global__ __launch_bounds__(256) void ynorm_kernel(
    const float* __restrict__ x, const float* __restrict__ dm,
    unsigned short* __restrict__ y, float* __restrict__ ninv, int D0)
{
  const int b = blockIdx.x, tid = threadIdx.x;
  const float4* x4 = (const float4*)(x + (size_t)b * D0);
  const float4* d4 = (const float4*)(dm + (size_t)b * D0);
  ushort4* y4 = (ushort4*)(y + (size_t)b * D0);
  const int n4 = D0 / 4;
  float ss = 0.f;
  for (int i = tid; i < n4; i += 256) {
    float4 xv = x4[i], dv = d4[i];
    ss += xv.x*xv.x + xv.y*xv.y + xv.z*xv.z + xv.w*xv.w;
    ushort4 o;
    o.x = f2bf(xv.x*dv.x); o.y = f2bf(xv.y*dv.y);
    o.z = f2bf(xv.z*dv.z); o.w = f2bf(xv.w*dv.w);
    y4[i] = o;
  }
  #pragma unroll
  for (int off = 32; off > 0; off >>= 1) ss += __shfl_down(ss, off);
  __shared__ float wsum[4];
  if ((tid & 63) == 0) wsum[tid >> 6] = ss;
  __syncthreads();
  if (tid == 0) {
    float t = wsum[0] + wsum[1] + wsum[2] + wsum[3];
    ninv[b] = 1.0f / fmaxf(sqrtf(t), 1e-12f);
  }
}

// per (b,l): gather proj rows over T tokens -> mean/std(ddof=1) -> prior
__global__ __launch_bounds__(256) void stats_kernel(
    const float* __restrict__ proj, const int* __restrict__ ids,
    const float* __restrict__ bi, const float* __restrict__ eps,
    float* __restrict__ prior, int T)
{
  const int b = blockIdx.x, l = threadIdx.x;
  __shared__ int sid[256];
  if (l < T) sid[l] = ids[b * T + l];
  __syncthreads();
  float s1 = 0.f, s2 = 0.f;
  #pragma unroll 4
  for (int t = 0; t < T; t++) {
    float p = proj[(size_t)sid[t] * 256 + l];
    s1 += p; s2 += p * p;
  }
  float var = fmaxf((s2 - s1 * s1 / (float)T) / (float)(T - 1), 0.f);
  float dev = sqrtf(var);                     // std, ddof=1
  float mean = s1 / (float)T + bi[l];
  prior[b * 256 + l] = mean + sqrtf(dev) * eps[b * 256 + l];
}

// h = bf16(tanh(ninv[b]*C1 + be1))
__global__ __launch_bounds__(256) void epi1_kernel(
    const float* __restrict__ C1, const float* __restrict__ ninv,
    const float* __restrict__ be1, unsigned short* __restrict__ h)
{
  int i = blockIdx.x * 256 + threadIdx.x;
  int b = i >> 10, n = i & 1023;
  h[i] = f2bf(tanhf(ninv[b] * C1[i] + be1[n]));
}

// split gparams -> mu/logvar outputs (+be2), z = bf16(prior*exp(0.5*lv)+mu)
__global__ __launch_bounds__(256) void z_kernel(
    const float* __restrict__ gp, const float* __restrict__ prior,
    const float* __restrict__ be2,
    float* __restrict__ out_mu, float* __restrict__ out_lv,
    unsigned short* __restrict__ z)
{
  int i = blockIdx.x * 256 + threadIdx.x;
  int b = i >> 8, l = i & 255;
  float mu = gp[b * 512 + l]       + be2[l];
  float lv = gp[b * 512 + 256 + l] + be2[256 + l];
  out_mu[i] = mu;
  out_lv[i] = lv;
  z[i] = f2bf(prior[i] * expf(0.5f * lv) + mu);
}

extern "C" void kernel_launch(void* const* d_in, const int* in_sizes, int n_in,
                              void* d_out, int out_size, void* d_ws, size_t ws_size,
                              hipStream_t stream)
{
  const float* x     = (const float*)d_in[0];
  const int*   ids   = (const int*)  d_in[1];
  const float* embed = (const float*)d_in[2];
  const float* Wi    = (const float*)d_in[3];
  const float* bi    = (const float*)d_in[4];
  const float* We1   = (const float*)d_in[5];
  const float* be1   = (const float*)d_in[6];
  const float* We2   = (const float*)d_in[7];
  const float* be2   = (const float*)d_in[8];
  const float* Wd1   = (const float*)d_in[9];
  const float* bd1   = (const float*)d_in[10];
  const float* Wd2   = (const float*)d_in[11];
  const float* bd2   = (const float*)d_in[12];
  const float* dm    = (const float*)d_in[13];
  const float* eps   = (const float*)d_in[14];

  constexpr int B = 512, T = 200, V = 3356, E = 1128, D0 = 20000, H = 1024, L = 256;

  char* w = (char*)d_ws;
  auto carve = [&](size_t bytes) { char* p = w; w += (bytes + 255) & ~(size_t)255; return p; };
  float*          proj  = (float*)         carve((size_t)V * L * 4);   // 3.44 MB
  unsigned short* y     = (unsigned short*)carve((size_t)B * D0 * 2);  // 20.5 MB
  float*          C1    = (float*)         carve((size_t)B * H * 4);   // 2 MB
  unsigned short* h     = (unsigned short*)carve((size_t)B * H * 2);
  float*          gp    = (float*)         carve((size_t)B * 2 * L * 4);
  float*          prior = (float*)         carve((size_t)B * L * 4);
  unsigned short* z     = (unsigned short*)carve((size_t)B * L * 2);
  unsigned short* hd    = (unsigned short*)carve((size_t)B * H * 2);
  float*          ninv  = (float*)         carve((size_t)B * 4);

  float* out_recon = (float*)d_out;
  float* out_mu    = out_recon + (size_t)B * D0;
  float* out_lv    = out_mu + (size_t)B * L;

  // y = bf16(x*dm), ninv = 1/||x||
  ynorm_kernel<<<B, 256, 0, stream>>>(x, dm, y, ninv, D0);
  // proj[v,l] = embed[v]·Wi[l]   (M=3356, N=256, K=1128), split-K=4 atomic
  hipMemsetAsync(proj, 0, (size_t)V * L * 4, stream);
  gemm_bt<float, float, 1><<<dim3(2, 27, 4), 256, 0, stream>>>(
      embed, Wi, nullptr, proj, nullptr, V, L, E, 288);
  // prior from gathered stats (adds bi)
  stats_kernel<<<B, 256, 0, stream>>>(proj, ids, bi, eps, prior, T);
  // GEMM1 (split-K=25): C1 = y @ We1^T
  hipMemsetAsync(C1, 0, (size_t)B * H * 4, stream);
  gemm_bt<unsigned short, float, 1><<<dim3(8, 4, 25), 256, 0, stream>>>(
      y, We1, nullptr, C1, nullptr, B, H, D0, 800);
  // h = tanh(ninv*C1 + be1)
  epi1_kernel<<<(B * H) / 256, 256, 0, stream>>>(C1, ninv, be1, h);
  // gparams = h @ We2^T (+be2 in z_kernel)  (M=512, N=512, K=1024), split-K=4
  hipMemsetAsync(gp, 0, (size_t)B * 2 * L * 4, stream);
  gemm_bt<unsigned short, float, 1><<<dim3(4, 4, 4), 256, 0, stream>>>(
      h, We2, nullptr, gp, nullptr, B, 2 * L, H, 256);
  // mu/logvar out, z
  z_kernel<<<(B * L) / 256, 256, 0, stream>>>(gp, prior, be2, out_mu, out_lv, z);
  // hd = tanh(z @ Wd1^T + bd1)  (M=512, N=1024, K=256)
  gemm_bt<unsigned short, float, 2><<<dim3(8, 4, 1), 256, 0, stream>>>(
      z, Wd1, bd1, nullptr, hd, B, H, L, 256);
  // recon = hd @ Wd2^T + bd2    (M=512, N=20000, K=1024)
  gemm_bt<unsigned short, float, 0><<<dim3(157, 4, 1), 256, 0, stream>>>(
      hd, Wd2, bd2, out_recon, nullptr, B, D0, H, 1024);
}

// Round 3
// 282.539 us; speedup vs baseline: 2.0458x; 2.0458x over previous
//
#include <hip/hip_runtime.h>
#include <hip/hip_bf16.h>

typedef __bf16 bf16x8 __attribute__((ext_vector_type(8)));
typedef float f32x4 __attribute__((ext_vector_type(4)));
typedef unsigned short u16x8 __attribute__((ext_vector_type(8)));

static __device__ __forceinline__ unsigned short f2bf(float f){
  unsigned int u = __float_as_uint(f);
  u += 0x7fffu + ((u >> 16) & 1u);   // round-to-nearest-even
  return (unsigned short)(u >> 16);
}

static __device__ __forceinline__ void gload16(const void* g, void* l){
  __builtin_amdgcn_global_load_lds(
      (const __attribute__((address_space(1))) unsigned int*)g,
      (__attribute__((address_space(3))) unsigned int*)l, 16, 0, 0);
}

// ---------------- DMA GEMM: C[m,n] = epi( sum_k A[m,k](bf16) * B[n,k](f32) )
// A:[M][K] bf16, B:[N][K] f32, both row-major. Tiles: BM=128, BN=64, BK=32.
// Staging via global_load_lds (linear LDS, per-lane global addresses).
// EPI 0: Cf = acc + bias(optional)  EPI 1: atomicAdd  EPI 2: Cbf = bf16(tanh(acc+bias))
template<int EPI>
__global__ __launch_bounds__(256) void gemm_dma(
    const unsigned short* __restrict__ A, const float* __restrict__ B,
    const float* __restrict__ bias,
    float* __restrict__ Cf, unsigned short* __restrict__ Cbf,
    int M, int N, int K, int kchunk)
{
  constexpr int BM = 128, BN = 64, BK = 32;
  __shared__ char smem[BM*BK*2 + BN*BK*4];          // 8KB A(bf16) + 8KB B(f32)
  unsigned short* lA = (unsigned short*)smem;
  float*          lB = (float*)(smem + BM*BK*2);

  const int tid  = threadIdx.x, lane = tid & 63, wave = tid >> 6;
  const int bm0  = blockIdx.y * BM, bn0 = blockIdx.x * BN;
  const int k0   = blockIdx.z * kchunk;
  const int kend = min(K, k0 + kchunk);             // kchunk, K multiples of 32 here
  const int fr = lane & 15, fq = lane >> 4;
  const int wm = (wave >> 1) * 64, wn = (wave & 1) * 32;

  // staging: waves 0,1 -> A chunks 0-3 / 4-7 (1KB = 16 rows of [128][32] bf16)
  //          waves 2,3 -> B chunks 0-3 / 4-7 (1KB =  8 rows of [64][32]  f32)
  const bool isA  = wave < 2;
  const int cbase = (wave & 1) * 4;
  const int arow = lane >> 2, acol = (lane & 3) * 8;   // A: 16B = 8 bf16
  const int brow = lane >> 3, bcol = (lane & 7) * 4;   // B: 16B = 4 f32

  f32x4 acc[4][2] = {};

  for (int kk = k0; kk < kend; kk += BK) {
    #pragma unroll
    for (int i = 0; i < 4; i++) {
      const int c = cbase + i;
      if (isA) {
        int r = min(bm0 + c*16 + arow, M - 1);
        gload16(A + (size_t)r * K + kk + acol, (char*)lA + c * 1024);
      } else {
        int r = min(bn0 + c*8 + brow, N - 1);
        gload16(B + (size_t)r * K + kk + bcol, (char*)lB + c * 1024);
      }
    }
    __syncthreads();                                   // drain DMA (vmcnt) + rendezvous

    u16x8 af[4], bg[2];
    #pragma unroll
    for (int i = 0; i < 4; i++)
      af[i] = *(const u16x8*)&lA[(wm + i*16 + fr) * BK + fq * 8];
    #pragma unroll
    for (int j = 0; j < 2; j++) {
      const float* bp = &lB[(wn + j*16 + fr) * BK + fq * 8];
      f32x4 t0 = *(const f32x4*)bp;
      f32x4 t1 = *(const f32x4*)(bp + 4);
      u16x8 b;
      #pragma unroll
      for (int e = 0; e < 4; e++) { b[e] = f2bf(t0[e]); b[e+4] = f2bf(t1[e]); }
      bg[j] = b;
    }
    #pragma unroll
    for (int i = 0; i < 4; i++)
      #pragma unroll
      for (int j = 0; j < 2; j++)
        acc[i][j] = __builtin_amdgcn_mfma_f32_16x16x32_bf16(
            __builtin_bit_cast(bf16x8, af[i]),
            __builtin_bit_cast(bf16x8, bg[j]),
            acc[i][j], 0, 0, 0);
    __syncthreads();                                   // reads done before next stage
  }

  #pragma unroll
  for (int i = 0; i < 4; i++)
    #pragma unroll
    for (int j = 0; j < 2; j++)
      #pragma unroll
      for (int r = 0; r < 4; r++) {
        int row = bm0 + wm + i*16 + fq*4 + r;
        int col = bn0 + wn + j*16 + fr;
        if (row < M && col < N) {
          float v = acc[i][j][r];
          if constexpr (EPI == 0) {
            Cf[(size_t)row * N + col] = v + (bias ? bias[col] : 0.0f);
          } else if constexpr (EPI == 1) {
            atomicAdd(&Cf[(size_t)row * N + col], v);
          } else {
            Cbf[(size_t)row * N + col] = f2bf(tanhf(v + bias[col]));
          }
        }
      }
}

// ---------------- reg-staged GEMM (round-1 proven) — only for proj (K=1128 not /32)
template<typename T>
static __device__ __forceinline__ u16x8 load8bf(const T* __restrict__ p, bool ok){
  u16x8 r;
  if (!ok) { r = (u16x8)0; return r; }
  if constexpr (sizeof(T) == 2) {
    r = *(const u16x8*)p;
  } else {
    const float4* q = (const float4*)p;
    float4 a = q[0], b = q[1];
    r[0]=f2bf(a.x); r[1]=f2bf(a.y); r[2]=f2bf(a.z); r[3]=f2bf(a.w);
    r[4]=f2bf(b.x); r[5]=f2bf(b.y); r[6]=f2bf(b.z); r[7]=f2bf(b.w);
  }
  return r;
}

__global__ __launch_bounds__(256) void gemm_reg_atomic(
    const float* __restrict__ A, const float* __restrict__ B,
    float* __restrict__ Cf, int M, int N, int K, int kchunk)
{
  constexpr int BM = 128, BN = 128, BK = 32, SA = 40;
  __shared__ unsigned short lA[BM*SA + BN*SA];
  unsigned short* lB = lA + BM*SA;

  const int tid  = threadIdx.x;
  const int bm0  = blockIdx.y * BM, bn0 = blockIdx.x * BN;
  const int k0   = blockIdx.z * kchunk;
  const int kend = min(K, k0 + kchunk);
  const int lane = tid & 63, wave = tid >> 6;
  const int wm = (wave >> 1) * 64, wn = (wave & 1) * 64;
  const int fr = lane & 15, fq = lane >> 4;
  const int srow = tid >> 1, shalf = tid & 1;

  f32x4 acc[4][4] = {};

  for (int kk = k0; kk < kend; kk += BK) {
    u16x8 va[2], vb[2];
    const int ac = kk + shalf * 16;
    {
      const int ar = bm0 + srow; const bool rok = ar < M;
      #pragma unroll
      for (int c = 0; c < 2; c++)
        va[c] = load8bf(A + (size_t)ar * K + ac + c * 8, rok && (ac + c * 8 < kend));
      const int br = bn0 + srow; const bool bok = br < N;
      #pragma unroll
      for (int c = 0; c < 2; c++)
        vb[c] = load8bf(B + (size_t)br * K + ac + c * 8, bok && (ac + c * 8 < kend));
    }
    __syncthreads();
    *(u16x8*)&lA[srow*SA + shalf*16 + 0] = va[0];
    *(u16x8*)&lA[srow*SA + shalf*16 + 8] = va[1];
    *(u16x8*)&lB[srow*SA + shalf*16 + 0] = vb[0];
    *(u16x8*)&lB[srow*SA + shalf*16 + 8] = vb[1];
    __syncthreads();

    u16x8 af[4], bg[4];
    #pragma unroll
    for (int i = 0; i < 4; i++) af[i] = *(const u16x8*)&lA[(wm + i*16 + fr)*SA + fq*8];
    #pragma unroll
    for (int j = 0; j < 4; j++) bg[j] = *(const u16x8*)&lB[(wn + j*16 + fr)*SA + fq*8];
    #pragma unroll
    for (int i = 0; i < 4; i++)
      #pragma unroll
      for (int j = 0; j < 4; j++)
        acc[i][j] = __builtin_amdgcn_mfma_f32_16x16x32_bf16(
            __builtin_bit_cast(bf16x8, af[i]),
            __builtin_bit_cast(bf16x8, bg[j]),
            acc[i][j], 0, 0, 0);
  }

  #pragma unroll
  for (int i = 0; i < 4; i++)
    #pragma unroll
    for (int j = 0; j < 4; j++)
      #pragma unroll
      for (int r = 0; r < 4; r++) {
        int row = bm0 + wm + i*16 + fq*4 + r;
        int col = bn0 + wn + j*16 + fr;
        if (row < M && col < N)
          atomicAdd(&Cf[(size_t)row * N + col], acc[i][j][r]);
      }
}

// ---------------- elementwise / reduction kernels ----------------
__global__ __launch_bounds__(256) void ynorm_kernel(
    const float* __restrict__ x, const float* __restrict__ dm,
    unsigned short* __restrict__ y, float* __restrict__ ninv, int D0)
{
  const int b = blockIdx.x, tid = threadIdx.x;
  const float4* x4 = (const float4*)(x + (size_t)b * D0);
  const float4* d4 = (const float4*)(dm + (size_t)b * D0);
  ushort4* y4 = (ushort4*)(y + (size_t)b * D0);
  const int n4 = D0 / 4;
  float ss = 0.f;
  for (int i = tid; i < n4; i += 256) {
    float4 xv = x4[i], dv = d4[i];
    ss += xv.x*xv.x + xv.y*xv.y + xv.z*xv.z + xv.w*xv.w;
    ushort4 o;
    o.x = f2bf(xv.x*dv.x); o.y = f2bf(xv.y*dv.y);
    o.z = f2bf(xv.z*dv.z); o.w = f2bf(xv.w*dv.w);
    y4[i] = o;
  }
  #pragma unroll
  for (int off = 32; off > 0; off >>= 1) ss += __shfl_down(ss, off);
  __shared__ float wsum[4];
  if ((tid & 63) == 0) wsum[tid >> 6] = ss;
  __syncthreads();
  if (tid == 0) {
    float t = wsum[0] + wsum[1] + wsum[2] + wsum[3];
    ninv[b] = 1.0f / fmaxf(sqrtf(t), 1e-12f);
  }
}

__global__ __launch_bounds__(256) void stats_kernel(
    const float* __restrict__ proj, const int* __restrict__ ids,
    const float* __restrict__ bi, const float* __restrict__ eps,
    float* __restrict__ prior, int T)
{
  const int b = blockIdx.x, l = threadIdx.x;
  __shared__ int sid[256];
  if (l < T) sid[l] = ids[b * T + l];
  __syncthreads();
  float s1 = 0.f, s2 = 0.f;
  #pragma unroll 4
  for (int t = 0; t < T; t++) {
    float p = proj[(size_t)sid[t] * 256 + l];
    s1 += p; s2 += p * p;
  }
  float var = fmaxf((s2 - s1 * s1 / (float)T) / (float)(T - 1), 0.f);
  float dev = sqrtf(var);
  float mean = s1 / (float)T + bi[l];
  prior[b * 256 + l] = mean + sqrtf(dev) * eps[b * 256 + l];
}

__global__ __launch_bounds__(256) void epi1_kernel(
    const float* __restrict__ C1, const float* __restrict__ ninv,
    const float* __restrict__ be1, unsigned short* __restrict__ h)
{
  int i = blockIdx.x * 256 + threadIdx.x;
  int b = i >> 10, n = i & 1023;
  h[i] = f2bf(tanhf(ninv[b] * C1[i] + be1[n]));
}

__global__ __launch_bounds__(256) void z_kernel(
    const float* __restrict__ gp, const float* __restrict__ prior,
    const float* __restrict__ be2,
    float* __restrict__ out_mu, float* __restrict__ out_lv,
    unsigned short* __restrict__ z)
{
  int i = blockIdx.x * 256 + threadIdx.x;
  int b = i >> 8, l = i & 255;
  float mu = gp[b * 512 + l]       + be2[l];
  float lv = gp[b * 512 + 256 + l] + be2[256 + l];
  out_mu[i] = mu;
  out_lv[i] = lv;
  z[i] = f2bf(prior[i] * expf(0.5f * lv) + mu);
}

extern "C" void kernel_launch(void* const* d_in, const int* in_sizes, int n_in,
                              void* d_out, int out_size, void* d_ws, size_t ws_size,
                              hipStream_t stream)
{
  const float* x     = (const float*)d_in[0];
  const int*   ids   = (const int*)  d_in[1];
  const float* embed = (const float*)d_in[2];
  const float* Wi    = (const float*)d_in[3];
  const float* bi    = (const float*)d_in[4];
  const float* We1   = (const float*)d_in[5];
  const float* be1   = (const float*)d_in[6];
  const float* We2   = (const float*)d_in[7];
  const float* be2   = (const float*)d_in[8];
  const float* Wd1   = (const float*)d_in[9];
  const float* bd1   = (const float*)d_in[10];
  const float* Wd2   = (const float*)d_in[11];
  const float* bd2   = (const float*)d_in[12];
  const float* dm    = (const float*)d_in[13];
  const float* eps   = (const float*)d_in[14];

  constexpr int B = 512, T = 200, V = 3356, E = 1128, D0 = 20000, H = 1024, L = 256;

  char* w = (char*)d_ws;
  auto carve = [&](size_t bytes) { char* p = w; w += (bytes + 255) & ~(size_t)255; return p; };
  float*          proj  = (float*)         carve((size_t)V * L * 4);
  unsigned short* y     = (unsigned short*)carve((size_t)B * D0 * 2);
  float*          C1    = (float*)         carve((size_t)B * H * 4);
  unsigned short* h     = (unsigned short*)carve((size_t)B * H * 2);
  float*          gp    = (float*)         carve((size_t)B * 2 * L * 4);
  float*          prior = (float*)         carve((size_t)B * L * 4);
  unsigned short* z     = (unsigned short*)carve((size_t)B * L * 2);
  unsigned short* hd    = (unsigned short*)carve((size_t)B * H * 2);
  float*          ninv  = (float*)         carve((size_t)B * 4);

  float* out_recon = (float*)d_out;
  float* out_mu    = out_recon + (size_t)B * D0;
  float* out_lv    = out_mu + (size_t)B * L;

  // y = bf16(x*dm), ninv = 1/||x||
  ynorm_kernel<<<B, 256, 0, stream>>>(x, dm, y, ninv, D0);
  // proj[v,l] = embed[v]·Wi[l]  (M=3356, N=256, K=1128) — reg path (K not /32), split-K=4
  hipMemsetAsync(proj, 0, (size_t)V * L * 4, stream);
  gemm_reg_atomic<<<dim3(2, 27, 4), 256, 0, stream>>>(embed, Wi, proj, V, L, E, 288);
  // prior from gathered stats (adds bi)
  stats_kernel<<<B, 256, 0, stream>>>(proj, ids, bi, eps, prior, T);
  // GEMM1: C1 = y @ We1^T  (M=512, N=1024, K=20000), split-K=25
  hipMemsetAsync(C1, 0, (size_t)B * H * 4, stream);
  gemm_dma<1><<<dim3(16, 4, 25), 256, 0, stream>>>(
      y, We1, nullptr, C1, nullptr, B, H, D0, 800);
  // h = tanh(ninv*C1 + be1)
  epi1_kernel<<<(B * H) / 256, 256, 0, stream>>>(C1, ninv, be1, h);
  // gparams = h @ We2^T (+be2 in z_kernel)  (M=512, N=512, K=1024), split-K=8
  hipMemsetAsync(gp, 0, (size_t)B * 2 * L * 4, stream);
  gemm_dma<1><<<dim3(8, 4, 8), 256, 0, stream>>>(
      h, We2, nullptr, gp, nullptr, B, 2 * L, H, 128);
  // mu/logvar out, z
  z_kernel<<<(B * L) / 256, 256, 0, stream>>>(gp, prior, be2, out_mu, out_lv, z);
  // hd = tanh(z @ Wd1^T + bd1)  (M=512, N=1024, K=256)
  gemm_dma<2><<<dim3(16, 4, 1), 256, 0, stream>>>(
      z, Wd1, bd1, nullptr, hd, B, H, L, 256);
  // recon = hd @ Wd2^T + bd2   (M=512, N=20000, K=1024)
  gemm_dma<0><<<dim3(313, 4, 1), 256, 0, stream>>>(
      hd, Wd2, bd2, out_recon, nullptr, B, D0, H, 1024);
}